// Round 1
// baseline (3294.347 us; speedup 1.0000x reference)
//
#include <hip/hip_runtime.h>
#include <hip/hip_bf16.h>
#include <math.h>

#define T_TOK 4096
#define H_DIM 2048
#define I_DIM 2048
#define N_EXP 8
#define CAP   4096   // worst-case tokens per expert

// ---------------------------------------------------------------------------
// Router: 1 wave per token. Each lane accumulates 8 expert logits over its
// 32 h-slices, shfl-xor reduce, lane 0 does top-2 + softmax + bucket append.
// ---------------------------------------------------------------------------
__global__ __launch_bounds__(256) void router_kernel(
    const float* __restrict__ x, const float* __restrict__ rw,
    int* __restrict__ counts, int* __restrict__ tok_list,
    float* __restrict__ scale_list) {
  int wave = threadIdx.x >> 6;
  int lane = threadIdx.x & 63;
  int t = blockIdx.x * 4 + wave;
  if (t >= T_TOK) return;

  float acc[N_EXP];
#pragma unroll
  for (int e = 0; e < N_EXP; ++e) acc[e] = 0.f;

  const float* xrow = x + (size_t)t * H_DIM;
  for (int h = lane; h < H_DIM; h += 64) {
    float xv = xrow[h];
    const float4 r0 = *(const float4*)(rw + (size_t)h * N_EXP);
    const float4 r1 = *(const float4*)(rw + (size_t)h * N_EXP + 4);
    acc[0] = fmaf(xv, r0.x, acc[0]);
    acc[1] = fmaf(xv, r0.y, acc[1]);
    acc[2] = fmaf(xv, r0.z, acc[2]);
    acc[3] = fmaf(xv, r0.w, acc[3]);
    acc[4] = fmaf(xv, r1.x, acc[4]);
    acc[5] = fmaf(xv, r1.y, acc[5]);
    acc[6] = fmaf(xv, r1.z, acc[6]);
    acc[7] = fmaf(xv, r1.w, acc[7]);
  }
#pragma unroll
  for (int e = 0; e < N_EXP; ++e) {
    float v = acc[e];
#pragma unroll
    for (int off = 32; off > 0; off >>= 1) v += __shfl_xor(v, off, 64);
    acc[e] = v;
  }
  if (lane == 0) {
    // top-2 (ties -> lowest index, matching jax.lax.top_k)
    int i0 = 0; float v0 = acc[0];
#pragma unroll
    for (int e = 1; e < N_EXP; ++e)
      if (acc[e] > v0) { v0 = acc[e]; i0 = e; }
    int i1 = -1; float v1 = -INFINITY;
#pragma unroll
    for (int e = 0; e < N_EXP; ++e)
      if (e != i0 && acc[e] > v1) { v1 = acc[e]; i1 = e; }
    // softmax over (v0, v1); v0 >= v1 so it's already stable
    float e1 = expf(v1 - v0);
    float s0 = 1.f / (1.f + e1);
    float s1 = e1 * s0;
    int p0 = atomicAdd(&counts[i0], 1);
    tok_list[i0 * CAP + p0] = t;
    scale_list[i0 * CAP + p0] = s0;
    int p1 = atomicAdd(&counts[i1], 1);
    tok_list[i1 * CAP + p1] = t;
    scale_list[i1 * CAP + p1] = s1;
  }
}

__global__ void offs_kernel(const int* __restrict__ counts, int* __restrict__ offs) {
  if (threadIdx.x == 0) {
    int s = 0;
#pragma unroll
    for (int e = 0; e < N_EXP; ++e) { offs[e] = s; s += counts[e]; }
  }
}

// ---------------------------------------------------------------------------
// GEMM1 (fused gate+up+swiglu): act[slot, i] = silu(x@w1) * (x@w3)
// 64x64 tile, BK=16, 256 threads, 4x4 microtile per thread.
// A rows gathered via tok_list.
// ---------------------------------------------------------------------------
__global__ __launch_bounds__(256) void gemm1_kernel(
    const float* __restrict__ x, const float* __restrict__ w1,
    const float* __restrict__ w3, const int* __restrict__ counts,
    const int* __restrict__ offs, const int* __restrict__ tok_list,
    float* __restrict__ act) {
  int e = blockIdx.z;
  int cnt = counts[e];
  int row0 = blockIdx.y * 64;
  if (row0 >= cnt) return;
  int n0 = blockIdx.x * 64;

  __shared__ __align__(16) float As[16][68];   // transposed [k][row], padded
  __shared__ __align__(16) float Bs1[16][64];
  __shared__ __align__(16) float Bs3[16][64];

  int tid = threadIdx.x;
  int tx = tid & 15, ty = tid >> 4;

  const int* tl = tok_list + e * CAP;
  const float* w1e = w1 + (size_t)e * H_DIM * I_DIM;
  const float* w3e = w3 + (size_t)e * H_DIM * I_DIM;

  float accG[4][4] = {{0}}, accU[4][4] = {{0}};

  int lk = tid & 15;     // A-load k
  int lr = tid >> 4;     // A-load row base
  int lcol = tid & 63;   // B-load col
  int lkb = tid >> 6;    // B-load k base

  for (int k0 = 0; k0 < H_DIM; k0 += 16) {
#pragma unroll
    for (int p = 0; p < 4; ++p) {
      int row = lr + p * 16;
      int gr = row0 + row;
      float v = 0.f;
      if (gr < cnt) {
        int t = tl[gr];
        v = x[(size_t)t * H_DIM + k0 + lk];
      }
      As[lk][row] = v;
    }
#pragma unroll
    for (int p = 0; p < 4; ++p) {
      int k = lkb + p * 4;
      Bs1[k][lcol] = w1e[(size_t)(k0 + k) * I_DIM + n0 + lcol];
      Bs3[k][lcol] = w3e[(size_t)(k0 + k) * I_DIM + n0 + lcol];
    }
    __syncthreads();
#pragma unroll
    for (int kk = 0; kk < 16; ++kk) {
      const float4 a  = *(const float4*)&As[kk][ty * 4];
      const float4 b1 = *(const float4*)&Bs1[kk][tx * 4];
      const float4 b3 = *(const float4*)&Bs3[kk][tx * 4];
      const float av[4] = {a.x, a.y, a.z, a.w};
      const float bg[4] = {b1.x, b1.y, b1.z, b1.w};
      const float bu[4] = {b3.x, b3.y, b3.z, b3.w};
#pragma unroll
      for (int m = 0; m < 4; ++m)
#pragma unroll
        for (int n = 0; n < 4; ++n) {
          accG[m][n] = fmaf(av[m], bg[n], accG[m][n]);
          accU[m][n] = fmaf(av[m], bu[n], accU[m][n]);
        }
    }
    __syncthreads();
  }

  int base = offs[e];
#pragma unroll
  for (int m = 0; m < 4; ++m) {
    int gr = row0 + ty * 4 + m;
    if (gr < cnt) {
      float o[4];
#pragma unroll
      for (int n = 0; n < 4; ++n) {
        float g = accG[m][n];
        float u = accU[m][n];
        o[n] = (g / (1.f + expf(-g))) * u;   // silu(g) * u
      }
      *(float4*)&act[(size_t)(base + gr) * I_DIM + n0 + tx * 4] = *(float4*)o;
    }
  }
}

// ---------------------------------------------------------------------------
// GEMM2: y = act @ w2[e]; out[tok] += scale * y  (atomicAdd combine)
// ---------------------------------------------------------------------------
__global__ __launch_bounds__(256) void gemm2_kernel(
    const float* __restrict__ act, const float* __restrict__ w2,
    const int* __restrict__ counts, const int* __restrict__ offs,
    const int* __restrict__ tok_list, const float* __restrict__ scale_list,
    float* __restrict__ out) {
  int e = blockIdx.z;
  int cnt = counts[e];
  int row0 = blockIdx.y * 64;
  if (row0 >= cnt) return;
  int n0 = blockIdx.x * 64;

  __shared__ __align__(16) float As[16][68];
  __shared__ __align__(16) float Bs[16][64];

  int tid = threadIdx.x;
  int tx = tid & 15, ty = tid >> 4;

  const float* w2e = w2 + (size_t)e * I_DIM * H_DIM;
  int base = offs[e];

  float acc[4][4] = {{0}};

  int lk = tid & 15;
  int lr = tid >> 4;
  int lcol = tid & 63;
  int lkb = tid >> 6;

  for (int k0 = 0; k0 < I_DIM; k0 += 16) {
#pragma unroll
    for (int p = 0; p < 4; ++p) {
      int row = lr + p * 16;
      int gr = row0 + row;
      float v = 0.f;
      if (gr < cnt) v = act[(size_t)(base + gr) * I_DIM + k0 + lk];
      As[lk][row] = v;
    }
#pragma unroll
    for (int p = 0; p < 4; ++p) {
      int k = lkb + p * 4;
      Bs[k][lcol] = w2e[(size_t)(k0 + k) * H_DIM + n0 + lcol];
    }
    __syncthreads();
#pragma unroll
    for (int kk = 0; kk < 16; ++kk) {
      const float4 a = *(const float4*)&As[kk][ty * 4];
      const float4 b = *(const float4*)&Bs[kk][tx * 4];
      const float av[4] = {a.x, a.y, a.z, a.w};
      const float bv[4] = {b.x, b.y, b.z, b.w};
#pragma unroll
      for (int m = 0; m < 4; ++m)
#pragma unroll
        for (int n = 0; n < 4; ++n)
          acc[m][n] = fmaf(av[m], bv[n], acc[m][n]);
    }
    __syncthreads();
  }

#pragma unroll
  for (int m = 0; m < 4; ++m) {
    int gr = row0 + ty * 4 + m;
    if (gr < cnt) {
      int t = tok_list[e * CAP + gr];
      float s = scale_list[e * CAP + gr];
      float* orow = out + (size_t)t * H_DIM + n0 + tx * 4;
#pragma unroll
      for (int n = 0; n < 4; ++n)
        atomicAdd(&orow[n], s * acc[m][n]);
    }
  }
}

// ---------------------------------------------------------------------------
extern "C" void kernel_launch(void* const* d_in, const int* in_sizes, int n_in,
                              void* d_out, int out_size, void* d_ws, size_t ws_size,
                              hipStream_t stream) {
  const float* x  = (const float*)d_in[0];
  const float* rw = (const float*)d_in[1];
  const float* w1 = (const float*)d_in[2];
  const float* w3 = (const float*)d_in[3];
  const float* w2 = (const float*)d_in[4];
  float* out = (float*)d_out;

  char* ws = (char*)d_ws;
  int*   counts     = (int*)ws;                       // 8 ints
  int*   offs       = (int*)(ws + 64);                // 8 ints
  int*   tok_list   = (int*)(ws + 256);               // 8*4096 ints (128 KB)
  float* scale_list = (float*)(ws + 256 + N_EXP * CAP * 4);  // 128 KB
  float* act        = (float*)(ws + (1 << 20));       // 8192*2048 fp32 = 64 MB

  hipMemsetAsync(counts, 0, 64, stream);
  hipMemsetAsync(out, 0, (size_t)T_TOK * H_DIM * sizeof(float), stream);

  router_kernel<<<T_TOK / 4, 256, 0, stream>>>(x, rw, counts, tok_list, scale_list);
  offs_kernel<<<1, 64, 0, stream>>>(counts, offs);

  dim3 grid(I_DIM / 64, CAP / 64, N_EXP);  // early-exit on rows >= count[e]
  gemm1_kernel<<<grid, 256, 0, stream>>>(x, w1, w3, counts, offs, tok_list, act);
  gemm2_kernel<<<grid, 256, 0, stream>>>(act, w2, counts, offs, tok_list, scale_list, out);
}

// Round 2
// 839.831 us; speedup vs baseline: 3.9226x; 3.9226x over previous
//
#include <hip/hip_runtime.h>
#include <hip/hip_bf16.h>
#include <math.h>

#define T_TOK 4096
#define H_DIM 2048
#define I_DIM 2048
#define N_EXP 8
#define CAP   4096
#define NK1   (H_DIM / 64)
#define NK2   (I_DIM / 64)

typedef __attribute__((ext_vector_type(8))) short short8;
typedef __attribute__((ext_vector_type(8))) __bf16 bf16v8;
typedef __attribute__((ext_vector_type(4))) float f32x4;

__device__ __forceinline__ short8 cvt8(const float* r) {
  bf16v8 h;
#pragma unroll
  for (int j = 0; j < 8; ++j) h[j] = (__bf16)r[j];
  return __builtin_bit_cast(short8, h);
}
__device__ __forceinline__ short f2bf(float f) {
  return __builtin_bit_cast(short, (__bf16)f);
}

// ---------------------------------------------------------------------------
// x fp32 -> bf16
// ---------------------------------------------------------------------------
__global__ __launch_bounds__(256) void convert_x_kernel(
    const float* __restrict__ x, short* __restrict__ xb) {
  int i = (blockIdx.x * 256 + threadIdx.x) * 8;
  float r[8];
  *(float4*)&r[0] = *(const float4*)(x + i);
  *(float4*)&r[4] = *(const float4*)(x + i + 4);
  *(short8*)(xb + i) = cvt8(r);
}

// ---------------------------------------------------------------------------
// Router: 1 wave per token; top-2 + softmax + bucket append. (proven round 1)
// ---------------------------------------------------------------------------
__global__ __launch_bounds__(256) void router_kernel(
    const float* __restrict__ x, const float* __restrict__ rw,
    int* __restrict__ counts, int* __restrict__ tok_list,
    float* __restrict__ scale_list) {
  int wave = threadIdx.x >> 6;
  int lane = threadIdx.x & 63;
  int t = blockIdx.x * 4 + wave;
  if (t >= T_TOK) return;

  float acc[N_EXP];
#pragma unroll
  for (int e = 0; e < N_EXP; ++e) acc[e] = 0.f;

  const float* xrow = x + (size_t)t * H_DIM;
  for (int h = lane; h < H_DIM; h += 64) {
    float xv = xrow[h];
    const float4 r0 = *(const float4*)(rw + (size_t)h * N_EXP);
    const float4 r1 = *(const float4*)(rw + (size_t)h * N_EXP + 4);
    acc[0] = fmaf(xv, r0.x, acc[0]);
    acc[1] = fmaf(xv, r0.y, acc[1]);
    acc[2] = fmaf(xv, r0.z, acc[2]);
    acc[3] = fmaf(xv, r0.w, acc[3]);
    acc[4] = fmaf(xv, r1.x, acc[4]);
    acc[5] = fmaf(xv, r1.y, acc[5]);
    acc[6] = fmaf(xv, r1.z, acc[6]);
    acc[7] = fmaf(xv, r1.w, acc[7]);
  }
#pragma unroll
  for (int e = 0; e < N_EXP; ++e) {
    float v = acc[e];
#pragma unroll
    for (int off = 32; off > 0; off >>= 1) v += __shfl_xor(v, off, 64);
    acc[e] = v;
  }
  if (lane == 0) {
    int i0 = 0; float v0 = acc[0];
#pragma unroll
    for (int e = 1; e < N_EXP; ++e)
      if (acc[e] > v0) { v0 = acc[e]; i0 = e; }
    int i1 = -1; float v1 = -INFINITY;
#pragma unroll
    for (int e = 0; e < N_EXP; ++e)
      if (e != i0 && acc[e] > v1) { v1 = acc[e]; i1 = e; }
    float e1 = expf(v1 - v0);
    float s0 = 1.f / (1.f + e1);
    float s1 = e1 * s0;
    int p0 = atomicAdd(&counts[i0], 1);
    tok_list[i0 * CAP + p0] = t;
    scale_list[i0 * CAP + p0] = s0;
    int p1 = atomicAdd(&counts[i1], 1);
    tok_list[i1 * CAP + p1] = t;
    scale_list[i1 * CAP + p1] = s1;
  }
}

__global__ void offs_kernel(const int* __restrict__ counts, int* __restrict__ offs) {
  if (threadIdx.x == 0) {
    int s = 0;
#pragma unroll
    for (int e = 0; e < N_EXP; ++e) { offs[e] = s; s += counts[e]; }
  }
}

// ---------------------------------------------------------------------------
// GEMM1: act[slot, i] = silu(x@w1[e]) * (x@w3[e]), bf16 MFMA.
// BM=256 (gathered rows), BN=64 per matrix, BK=64, 512 threads (8 waves).
// Wave (wid): rows (wid>>1)*64, cols (wid&1)*32 of each matrix.
// LDS rows = 64 bf16 (128 B), chunk-XOR swizzle (c ^ (row&7)).
// ---------------------------------------------------------------------------
__global__ __launch_bounds__(512) void gemm1_kernel(
    const short* __restrict__ xb, const float* __restrict__ w1,
    const float* __restrict__ w3, const int* __restrict__ counts,
    const int* __restrict__ offs, const int* __restrict__ tok_list,
    short* __restrict__ act) {
  const int e = blockIdx.z;
  const int cnt = counts[e];
  const int row0 = blockIdx.y * 256;
  if (row0 >= cnt) return;
  const int n0 = blockIdx.x * 64;

  __shared__ short As[256 * 64];   // 32 KB
  __shared__ short B1s[64 * 64];   // 8 KB
  __shared__ short B3s[64 * 64];   // 8 KB

  const int tid = threadIdx.x;
  const int lane = tid & 63;
  const int wid = tid >> 6;

  const float* w1e = w1 + (size_t)e * H_DIM * I_DIM;
  const float* w3e = w3 + (size_t)e * H_DIM * I_DIM;

  // A staging map: thread -> (row, k-half of 32)
  const int arow = tid >> 1;
  const int ahalf = tid & 1;
  const int gr_a = row0 + arow;
  const int tok = (gr_a < cnt) ? tok_list[e * CAP + gr_a] : -1;
  const short* asrc = (tok >= 0) ? (xb + (size_t)tok * H_DIM + ahalf * 32) : (const short*)0;

  // B staging map: thread -> (n, 8 k's)
  const int bn = tid & 63;
  const int bkc = wid;  // k-chunk index (8 bf16 each)
  const float* b1p = w1e + (size_t)(bkc * 8) * I_DIM + n0 + bn;
  const float* b3p = w3e + (size_t)(bkc * 8) * I_DIM + n0 + bn;

  // wave tile
  const int wm = (wid >> 1) * 64;
  const int wn = (wid & 1) * 32;
  const int fr = lane & 15;
  const int fg = lane >> 4;
  const int sx = fr & 7;

  f32x4 accG[4][2], accU[4][2];
#pragma unroll
  for (int mi = 0; mi < 4; ++mi)
#pragma unroll
    for (int ni = 0; ni < 2; ++ni) {
      accG[mi][ni] = (f32x4)0.f;
      accU[mi][ni] = (f32x4)0.f;
    }

  short8 aS[4];
  float bS1[8], bS3[8];

#define G1_LOADS(K0)                                                        \
  {                                                                         \
    if (asrc) {                                                             \
      _Pragma("unroll") for (int c = 0; c < 4; ++c)                         \
          aS[c] = *(const short8*)(asrc + (K0) + c * 8);                    \
    } else {                                                                \
      _Pragma("unroll") for (int c = 0; c < 4; ++c) aS[c] = (short8)0;      \
    }                                                                       \
    _Pragma("unroll") for (int j = 0; j < 8; ++j)                           \
        bS1[j] = b1p[(size_t)((K0) + j) * I_DIM];                           \
    _Pragma("unroll") for (int j = 0; j < 8; ++j)                           \
        bS3[j] = b3p[(size_t)((K0) + j) * I_DIM];                           \
  }

#define G1_WRITE()                                                          \
  {                                                                         \
    _Pragma("unroll") for (int c = 0; c < 4; ++c) {                         \
      int ch = 4 * ahalf + c;                                               \
      *(short8*)&As[arow * 64 + ((ch ^ (arow & 7)) << 3)] = aS[c];          \
    }                                                                       \
    *(short8*)&B1s[bn * 64 + ((bkc ^ (bn & 7)) << 3)] = cvt8(bS1);          \
    *(short8*)&B3s[bn * 64 + ((bkc ^ (bn & 7)) << 3)] = cvt8(bS3);          \
  }

  G1_LOADS(0)
  G1_WRITE()
  __syncthreads();

  for (int kt = 0; kt < NK1; ++kt) {
    const bool more = (kt + 1) < NK1;
    if (more) G1_LOADS((kt + 1) * 64)

#pragma unroll
    for (int ks = 0; ks < 2; ++ks) {
      const int cb = ((ks << 2) + fg) ^ sx;
      short8 av[4], b1v[2], b3v[2];
#pragma unroll
      for (int mi = 0; mi < 4; ++mi)
        av[mi] = *(const short8*)&As[(wm + mi * 16 + fr) * 64 + (cb << 3)];
#pragma unroll
      for (int ni = 0; ni < 2; ++ni) {
        b1v[ni] = *(const short8*)&B1s[(wn + ni * 16 + fr) * 64 + (cb << 3)];
        b3v[ni] = *(const short8*)&B3s[(wn + ni * 16 + fr) * 64 + (cb << 3)];
      }
#pragma unroll
      for (int mi = 0; mi < 4; ++mi)
#pragma unroll
        for (int ni = 0; ni < 2; ++ni) {
          accG[mi][ni] = __builtin_amdgcn_mfma_f32_16x16x32_bf16(
              av[mi], b1v[ni], accG[mi][ni], 0, 0, 0);
          accU[mi][ni] = __builtin_amdgcn_mfma_f32_16x16x32_bf16(
              av[mi], b3v[ni], accU[mi][ni], 0, 0, 0);
        }
    }
    __syncthreads();
    if (more) G1_WRITE()
    __syncthreads();
  }

  const int base = offs[e];
#pragma unroll
  for (int mi = 0; mi < 4; ++mi) {
    const int rb = row0 + wm + mi * 16 + fg * 4;
#pragma unroll
    for (int ni = 0; ni < 2; ++ni) {
      const int col = n0 + wn + ni * 16 + fr;
#pragma unroll
      for (int r = 0; r < 4; ++r) {
        int gr = rb + r;
        if (gr < cnt) {
          float g = accG[mi][ni][r];
          float u = accU[mi][ni][r];
          float o = g / (1.f + __expf(-g)) * u;
          act[(size_t)(base + gr) * I_DIM + col] = f2bf(o);
        }
      }
    }
  }
}

// ---------------------------------------------------------------------------
// GEMM2: out[tok] += scale * (act @ w2[e]).  BM=256, BN=128, BK=64, 8 waves.
// Wave: rows (wid>>1)*64, cols (wid&1)*64.
// ---------------------------------------------------------------------------
__global__ __launch_bounds__(512) void gemm2_kernel(
    const short* __restrict__ act, const float* __restrict__ w2,
    const int* __restrict__ counts, const int* __restrict__ offs,
    const int* __restrict__ tok_list, const float* __restrict__ scale_list,
    float* __restrict__ out) {
  const int e = blockIdx.z;
  const int cnt = counts[e];
  const int row0 = blockIdx.y * 256;
  if (row0 >= cnt) return;
  const int n0 = blockIdx.x * 128;
  const int base = offs[e];

  __shared__ short As[256 * 64];   // 32 KB
  __shared__ short Bs[128 * 64];   // 16 KB

  const int tid = threadIdx.x;
  const int lane = tid & 63;
  const int wid = tid >> 6;

  const float* w2e = w2 + (size_t)e * I_DIM * H_DIM;

  const int arow = tid >> 1;
  const int ahalf = tid & 1;
  const int gr_a = row0 + arow;
  const short* asrc = (gr_a < cnt)
      ? (act + (size_t)(base + gr_a) * I_DIM + ahalf * 32) : (const short*)0;

  const int bn = tid & 127;             // 0..127
  const int bkc = (tid >> 7) * 2;       // k-chunk base (2 chunks of 8)
  const float* bp = w2e + (size_t)(bkc * 8) * H_DIM + n0 + bn;

  const int wm = (wid >> 1) * 64;
  const int wn = (wid & 1) * 64;
  const int fr = lane & 15;
  const int fg = lane >> 4;
  const int sx = fr & 7;

  f32x4 acc[4][4];
#pragma unroll
  for (int mi = 0; mi < 4; ++mi)
#pragma unroll
    for (int ni = 0; ni < 4; ++ni) acc[mi][ni] = (f32x4)0.f;

  short8 aS[4];
  float bS[16];

#define G2_LOADS(K0)                                                        \
  {                                                                         \
    if (asrc) {                                                             \
      _Pragma("unroll") for (int c = 0; c < 4; ++c)                         \
          aS[c] = *(const short8*)(asrc + (K0) + c * 8);                    \
    } else {                                                                \
      _Pragma("unroll") for (int c = 0; c < 4; ++c) aS[c] = (short8)0;      \
    }                                                                       \
    _Pragma("unroll") for (int j = 0; j < 16; ++j)                          \
        bS[j] = bp[(size_t)((K0) + j) * H_DIM];                             \
  }

#define G2_WRITE()                                                          \
  {                                                                         \
    _Pragma("unroll") for (int c = 0; c < 4; ++c) {                         \
      int ch = 4 * ahalf + c;                                               \
      *(short8*)&As[arow * 64 + ((ch ^ (arow & 7)) << 3)] = aS[c];          \
    }                                                                       \
    *(short8*)&Bs[bn * 64 + ((bkc ^ (bn & 7)) << 3)] = cvt8(bS);            \
    *(short8*)&Bs[bn * 64 + (((bkc + 1) ^ (bn & 7)) << 3)] = cvt8(bS + 8);  \
  }

  G2_LOADS(0)
  G2_WRITE()
  __syncthreads();

  for (int kt = 0; kt < NK2; ++kt) {
    const bool more = (kt + 1) < NK2;
    if (more) G2_LOADS((kt + 1) * 64)

#pragma unroll
    for (int ks = 0; ks < 2; ++ks) {
      const int cb = ((ks << 2) + fg) ^ sx;
      short8 av[4], bv[4];
#pragma unroll
      for (int mi = 0; mi < 4; ++mi)
        av[mi] = *(const short8*)&As[(wm + mi * 16 + fr) * 64 + (cb << 3)];
#pragma unroll
      for (int ni = 0; ni < 4; ++ni)
        bv[ni] = *(const short8*)&Bs[(wn + ni * 16 + fr) * 64 + (cb << 3)];
#pragma unroll
      for (int mi = 0; mi < 4; ++mi)
#pragma unroll
        for (int ni = 0; ni < 4; ++ni)
          acc[mi][ni] = __builtin_amdgcn_mfma_f32_16x16x32_bf16(
              av[mi], bv[ni], acc[mi][ni], 0, 0, 0);
    }
    __syncthreads();
    if (more) G2_WRITE()
    __syncthreads();
  }

#pragma unroll
  for (int mi = 0; mi < 4; ++mi) {
#pragma unroll
    for (int r = 0; r < 4; ++r) {
      int gr = row0 + wm + mi * 16 + fg * 4 + r;
      if (gr < cnt) {
        int t = tok_list[e * CAP + gr];
        float s = scale_list[e * CAP + gr];
        float* orow = out + (size_t)t * H_DIM + n0;
#pragma unroll
        for (int ni = 0; ni < 4; ++ni)
          atomicAdd(&orow[wn + ni * 16 + fr], s * acc[mi][ni][r]);
      }
    }
  }
}

// ---------------------------------------------------------------------------
extern "C" void kernel_launch(void* const* d_in, const int* in_sizes, int n_in,
                              void* d_out, int out_size, void* d_ws, size_t ws_size,
                              hipStream_t stream) {
  const float* x  = (const float*)d_in[0];
  const float* rw = (const float*)d_in[1];
  const float* w1 = (const float*)d_in[2];
  const float* w3 = (const float*)d_in[3];
  const float* w2 = (const float*)d_in[4];
  float* out = (float*)d_out;

  char* ws = (char*)d_ws;
  int*   counts     = (int*)ws;
  int*   offs       = (int*)(ws + 64);
  int*   tok_list   = (int*)(ws + 256);
  float* scale_list = (float*)(ws + 256 + N_EXP * CAP * 4);
  short* x_bf       = (short*)(ws + (1 << 20));
  short* act        = (short*)(ws + (1 << 20) + ((size_t)16 << 20));

  hipMemsetAsync(counts, 0, 64, stream);
  hipMemsetAsync(out, 0, (size_t)T_TOK * H_DIM * sizeof(float), stream);

  convert_x_kernel<<<(T_TOK * H_DIM) / (256 * 8), 256, 0, stream>>>(x, x_bf);
  router_kernel<<<T_TOK / 4, 256, 0, stream>>>(x, rw, counts, tok_list, scale_list);
  offs_kernel<<<1, 64, 0, stream>>>(counts, offs);

  dim3 g1(I_DIM / 64, T_TOK / 256, N_EXP);
  gemm1_kernel<<<g1, 512, 0, stream>>>(x_bf, w1, w3, counts, offs, tok_list, act);
  dim3 g2(H_DIM / 128, T_TOK / 256, N_EXP);
  gemm2_kernel<<<g2, 512, 0, stream>>>(act, w2, counts, offs, tok_list, scale_list, out);
}